// Round 6
// baseline (890.441 us; speedup 1.0000x reference)
//
#include <hip/hip_runtime.h>

#define BB 4
#define CC 128
#define NN 65536
#define HEADS 8
#define HD 16
#define TN 32
#define NTILES (NN / TN)   // 2048
#define TPB 256
#define K1_GRIDX 192       // blocks per batch for kernel1 (persistent, grid-stride)
#define QSTR 36            // padded LDS stride for Qs in k3
#define CCP 132            // padded chan-stride for transposed Ks/Vs (16B aligned)

// NOTE: macro params must NOT be named w/x/y/z — token substitution would
// rewrite the .w member access (that was R0's compile failure).
#define RANK1(acc_, wgt_, xv_)                  \
  (acc_)[0] = fmaf((wgt_), (xv_).x, (acc_)[0]); \
  (acc_)[1] = fmaf((wgt_), (xv_).y, (acc_)[1]); \
  (acc_)[2] = fmaf((wgt_), (xv_).z, (acc_)[2]); \
  (acc_)[3] = fmaf((wgt_), (xv_).w, (acc_)[3]);

// ---------------------------------------------------------------------------
// Kernel 1: ctx[b,h,i,j] = sum_n relu(Wk x + bk)[h*16+i, n] * (Wv x + bv)[h*16+j, n]
// KsT/VsT stored [col][chan] so stage B reads are vectorized (b128) and
// conflict-free (<=2-way). R4 rocprof: old [chan][col] layout cost 272 scalar
// ds_reads/thread/tile with 4-8 way conflicts -> 8.9M conflict cycles.
// ---------------------------------------------------------------------------
__global__ __launch_bounds__(TPB) void k1_context(
    const float* __restrict__ x,
    const float* __restrict__ Wk, const float* __restrict__ bk,
    const float* __restrict__ Wv, const float* __restrict__ bv,
    float* __restrict__ ctx)
{
  __shared__ float Xs[CC][TN];      // 16 KB
  __shared__ float KsT[TN][CCP];    // 16.5 KB  [col][chan]
  __shared__ float VsT[TN][CCP];    // 16.5 KB  -> ~49 KB total, 3 blocks/CU

  const int b  = blockIdx.y;
  const int t  = threadIdx.x;
  const int tc = t & 7, tr = t >> 3;     // proj mapping: 4 cols x 4 channels
  const int n0 = tc * 4, c0 = tr * 4;
  const int p  = t & 127, hf = t >> 7;   // stage-B mapping: (h,i) pair + column half
  const int h  = p >> 4, iq = p & 15;
  const int krow = h * HD + iq;

  float bK[4], bV[4];
#pragma unroll
  for (int cc = 0; cc < 4; ++cc) { bK[cc] = bk[c0 + cc]; bV[cc] = bv[c0 + cc]; }

  float ck[HD];
#pragma unroll
  for (int j = 0; j < HD; ++j) ck[j] = 0.f;

  const float* xb = x + (size_t)b * CC * NN;
  const float* wkRow0 = Wk + c0 * CC;
  const float* wkRow1 = Wk + (c0 + 1) * CC;
  const float* wkRow2 = Wk + (c0 + 2) * CC;
  const float* wkRow3 = Wk + (c0 + 3) * CC;
  const float* wvRow0 = Wv + c0 * CC;
  const float* wvRow1 = Wv + (c0 + 1) * CC;
  const float* wvRow2 = Wv + (c0 + 2) * CC;
  const float* wvRow3 = Wv + (c0 + 3) * CC;
  bool have = false;

  for (int tile = blockIdx.x; tile < NTILES; tile += K1_GRIDX) {
    const int nbase = tile * TN;

    // ---- load X tile (global -> LDS); overlaps with stage B of previous tile
    {
      const int g = t & 7, r0 = t >> 3;
#pragma unroll
      for (int k = 0; k < 4; ++k) {
        const int r = r0 + 32 * k;
        *(float4*)&Xs[r][g * 4] =
            *(const float4*)&xb[(size_t)r * NN + nbase + g * 4];
      }
    }

    // ---- stage B: context accumulation for PREVIOUS tile (reads KsT/VsT)
    if (have) {
#pragma unroll
      for (int cl = 0; cl < 16; ++cl) {
        const int col = hf * 16 + cl;
        const float kk = KsT[col][krow];
        const float4* vr = (const float4*)&VsT[col][h * HD];
        const float4 v0 = vr[0], v1 = vr[1], v2 = vr[2], v3 = vr[3];
        RANK1(&ck[0], kk, v0); RANK1(&ck[4], kk, v1);
        RANK1(&ck[8], kk, v2); RANK1(&ck[12], kk, v3);
      }
    }
    __syncthreads();  // Xs ready; everyone done reading KsT/VsT

    // ---- K and V projections (read Xs, write KsT/VsT), 1-ahead weight prefetch
    {
      float aK[4][4], aV[4][4];
#pragma unroll
      for (int a = 0; a < 4; ++a)
#pragma unroll
        for (int j = 0; j < 4; ++j) { aK[a][j] = 0.f; aV[a][j] = 0.f; }

      float4 wkb[2][4], wvb[2][4];
      wkb[0][0] = *(const float4*)&wkRow0[0];
      wkb[0][1] = *(const float4*)&wkRow1[0];
      wkb[0][2] = *(const float4*)&wkRow2[0];
      wkb[0][3] = *(const float4*)&wkRow3[0];
      wvb[0][0] = *(const float4*)&wvRow0[0];
      wvb[0][1] = *(const float4*)&wvRow1[0];
      wvb[0][2] = *(const float4*)&wvRow2[0];
      wvb[0][3] = *(const float4*)&wvRow3[0];

#pragma unroll 2
      for (int s = 0; s < 32; ++s) {
        const int cur = s & 1, nxt = cur ^ 1;
        const int ci = s * 4;
        const int cn = (s < 31) ? ci + 4 : ci;   // clamped prefetch addr
        wkb[nxt][0] = *(const float4*)&wkRow0[cn];
        wkb[nxt][1] = *(const float4*)&wkRow1[cn];
        wkb[nxt][2] = *(const float4*)&wkRow2[cn];
        wkb[nxt][3] = *(const float4*)&wkRow3[cn];
        wvb[nxt][0] = *(const float4*)&wvRow0[cn];
        wvb[nxt][1] = *(const float4*)&wvRow1[cn];
        wvb[nxt][2] = *(const float4*)&wvRow2[cn];
        wvb[nxt][3] = *(const float4*)&wvRow3[cn];

        const float4 x0 = *(const float4*)&Xs[ci + 0][n0];
        const float4 x1 = *(const float4*)&Xs[ci + 1][n0];
        const float4 x2 = *(const float4*)&Xs[ci + 2][n0];
        const float4 x3 = *(const float4*)&Xs[ci + 3][n0];
#pragma unroll
        for (int cc = 0; cc < 4; ++cc) {
          const float4 wk4 = wkb[cur][cc];
          const float4 wv4 = wvb[cur][cc];
          float* aK_ = aK[cc];
          float* aV_ = aV[cc];
          RANK1(aK_, wk4.x, x0); RANK1(aK_, wk4.y, x1);
          RANK1(aK_, wk4.z, x2); RANK1(aK_, wk4.w, x3);
          RANK1(aV_, wv4.x, x0); RANK1(aV_, wv4.y, x1);
          RANK1(aV_, wv4.z, x2); RANK1(aV_, wv4.w, x3);
        }
      }

      // transposed writes: per col, a float4 of 4 channels
#pragma unroll
      for (int cj = 0; cj < 4; ++cj) {
        float4 ko, vo;
        ko.x = fmaxf(aK[0][cj] + bK[0], 0.f);
        ko.y = fmaxf(aK[1][cj] + bK[1], 0.f);
        ko.z = fmaxf(aK[2][cj] + bK[2], 0.f);
        ko.w = fmaxf(aK[3][cj] + bK[3], 0.f);
        vo.x = aV[0][cj] + bV[0];
        vo.y = aV[1][cj] + bV[1];
        vo.z = aV[2][cj] + bV[2];
        vo.w = aV[3][cj] + bV[3];
        *(float4*)&KsT[n0 + cj][c0] = ko;
        *(float4*)&VsT[n0 + cj][c0] = vo;
      }
    }
    __syncthreads();  // KsT/VsT ready for stage B next iteration
    have = true;
  }

  // ---- stage B for the last tile
  if (have) {
#pragma unroll
    for (int cl = 0; cl < 16; ++cl) {
      const int col = hf * 16 + cl;
      const float kk = KsT[col][krow];
      const float4* vr = (const float4*)&VsT[col][h * HD];
      const float4 v0 = vr[0], v1 = vr[1], v2 = vr[2], v3 = vr[3];
      RANK1(&ck[0], kk, v0); RANK1(&ck[4], kk, v1);
      RANK1(&ck[8], kk, v2); RANK1(&ck[12], kk, v3);
    }
  }
  __syncthreads();

  // ---- reduce the two column-halves via LDS scratch (reuse Xs), then atomicAdd
  if (hf == 1) {
#pragma unroll
    for (int j = 0; j < HD; ++j) Xs[p][j] = ck[j];
  }
  __syncthreads();
  if (hf == 0) {
    float* cdst = ctx + (size_t)b * HEADS * HD * HD + krow * HD;
#pragma unroll
    for (int j = 0; j < HD; ++j) atomicAdd(&cdst[j], ck[j] + Xs[p][j]);
  }
}

// ---------------------------------------------------------------------------
// Kernel 2: M[b][o][h*16+i] = sum_j Wr[o, h*16+j] * ctx[b,h,i,j]
// ---------------------------------------------------------------------------
__global__ __launch_bounds__(TPB) void k2_fold(
    const float* __restrict__ Wr, const float* __restrict__ ctx,
    float* __restrict__ M)
{
  const int b = blockIdx.x;
  const int half = blockIdx.y;                  // o in [half*64, half*64+64)
  const float* cb = ctx + (size_t)b * HEADS * HD * HD;
  const int base = half * (CC / 2) * CC;        // 64*128 elements per half
  for (int k = threadIdx.x; k < (CC / 2) * CC; k += TPB) {
    const int idx = base + k;
    const int o = idx >> 7, c = idx & (CC - 1);
    const int h = c >> 4, i = c & 15;
    const float* cr = cb + h * HD * HD + i * HD;
    const float* wr = Wr + o * CC + h * HD;
    float s = 0.f;
#pragma unroll
    for (int j = 0; j < HD; ++j) s = fmaf(wr[j], cr[j], s);
    M[((size_t)b << 14) + idx] = s;
  }
}

// ---------------------------------------------------------------------------
// Kernel 3: out = M[b] @ relu(Wq x + bq) + br  (1-ahead prefetch on Wq and M)
// ---------------------------------------------------------------------------
__global__ __launch_bounds__(TPB) void k3_out(
    const float* __restrict__ x,
    const float* __restrict__ Wq, const float* __restrict__ bq,
    const float* __restrict__ M, const float* __restrict__ br,
    float* __restrict__ out)
{
  __shared__ float Xs[CC][TN];     // 16 KB
  __shared__ float Qs[CC][QSTR];   // 18 KB  -> 34 KB, 4 blocks/CU

  const int b = blockIdx.y;
  const int tile = blockIdx.x;
  const int t = threadIdx.x;
  const int tc = t & 7, tr = t >> 3;
  const int n0 = tc * 4, c0 = tr * 4;
  const int nbase = tile * TN;
  const float* xb = x + (size_t)b * CC * NN;
  const float* Mb = M + ((size_t)b << 14);

  // load X tile
  {
    const int g = t & 7, r0 = t >> 3;
#pragma unroll
    for (int k = 0; k < 4; ++k) {
      const int r = r0 + 32 * k;
      *(float4*)&Xs[r][g * 4] =
          *(const float4*)&xb[(size_t)r * NN + nbase + g * 4];
    }
  }
  __syncthreads();

  // Q projection (relu, bias) -> Qs, with weight prefetch
  {
    float aQ[4][4];
#pragma unroll
    for (int a = 0; a < 4; ++a)
#pragma unroll
      for (int j = 0; j < 4; ++j) aQ[a][j] = 0.f;

    const float* wq0 = Wq + c0 * CC;
    const float* wq1 = Wq + (c0 + 1) * CC;
    const float* wq2 = Wq + (c0 + 2) * CC;
    const float* wq3 = Wq + (c0 + 3) * CC;
    float4 wqb[2][4];
    wqb[0][0] = *(const float4*)&wq0[0];
    wqb[0][1] = *(const float4*)&wq1[0];
    wqb[0][2] = *(const float4*)&wq2[0];
    wqb[0][3] = *(const float4*)&wq3[0];

#pragma unroll 2
    for (int s = 0; s < 32; ++s) {
      const int cur = s & 1, nxt = cur ^ 1;
      const int ci = s * 4;
      const int cn = (s < 31) ? ci + 4 : ci;
      wqb[nxt][0] = *(const float4*)&wq0[cn];
      wqb[nxt][1] = *(const float4*)&wq1[cn];
      wqb[nxt][2] = *(const float4*)&wq2[cn];
      wqb[nxt][3] = *(const float4*)&wq3[cn];

      const float4 x0 = *(const float4*)&Xs[ci + 0][n0];
      const float4 x1 = *(const float4*)&Xs[ci + 1][n0];
      const float4 x2 = *(const float4*)&Xs[ci + 2][n0];
      const float4 x3 = *(const float4*)&Xs[ci + 3][n0];
#pragma unroll
      for (int cc = 0; cc < 4; ++cc) {
        const float4 wq4 = wqb[cur][cc];
        float* aQ_ = aQ[cc];
        RANK1(aQ_, wq4.x, x0); RANK1(aQ_, wq4.y, x1);
        RANK1(aQ_, wq4.z, x2); RANK1(aQ_, wq4.w, x3);
      }
    }
#pragma unroll
    for (int cc = 0; cc < 4; ++cc) {
      const float bb = bq[c0 + cc];
      float4 qo;
      qo.x = fmaxf(aQ[cc][0] + bb, 0.f);
      qo.y = fmaxf(aQ[cc][1] + bb, 0.f);
      qo.z = fmaxf(aQ[cc][2] + bb, 0.f);
      qo.w = fmaxf(aQ[cc][3] + bb, 0.f);
      *(float4*)&Qs[c0 + cc][n0] = qo;
    }
  }
  __syncthreads();

  // out tile = M @ Qs + br, with M prefetch
  {
    float aO[4][4];
#pragma unroll
    for (int a = 0; a < 4; ++a)
#pragma unroll
      for (int j = 0; j < 4; ++j) aO[a][j] = 0.f;

    const float* m0 = Mb + (c0 + 0) * CC;
    const float* m1 = Mb + (c0 + 1) * CC;
    const float* m2 = Mb + (c0 + 2) * CC;
    const float* m3 = Mb + (c0 + 3) * CC;
    float4 mb[2][4];
    mb[0][0] = *(const float4*)&m0[0];
    mb[0][1] = *(const float4*)&m1[0];
    mb[0][2] = *(const float4*)&m2[0];
    mb[0][3] = *(const float4*)&m3[0];

#pragma unroll 2
    for (int s = 0; s < 32; ++s) {
      const int cur = s & 1, nxt = cur ^ 1;
      const int c = s * 4;
      const int cn = (s < 31) ? c + 4 : c;
      mb[nxt][0] = *(const float4*)&m0[cn];
      mb[nxt][1] = *(const float4*)&m1[cn];
      mb[nxt][2] = *(const float4*)&m2[cn];
      mb[nxt][3] = *(const float4*)&m3[cn];

      const float4 q0 = *(const float4*)&Qs[c + 0][n0];
      const float4 q1 = *(const float4*)&Qs[c + 1][n0];
      const float4 q2 = *(const float4*)&Qs[c + 2][n0];
      const float4 q3 = *(const float4*)&Qs[c + 3][n0];
#pragma unroll
      for (int oo = 0; oo < 4; ++oo) {
        const float4 mw4 = mb[cur][oo];
        float* aO_ = aO[oo];
        RANK1(aO_, mw4.x, q0); RANK1(aO_, mw4.y, q1);
        RANK1(aO_, mw4.z, q2); RANK1(aO_, mw4.w, q3);
      }
    }
#pragma unroll
    for (int oo = 0; oo < 4; ++oo) {
      const float bb = br[c0 + oo];
      float4 vo;
      vo.x = aO[oo][0] + bb;
      vo.y = aO[oo][1] + bb;
      vo.z = aO[oo][2] + bb;
      vo.w = aO[oo][3] + bb;
      *(float4*)&out[((size_t)b * CC + (c0 + oo)) * NN + nbase + n0] = vo;
    }
  }
}

// ---------------------------------------------------------------------------
extern "C" void kernel_launch(void* const* d_in, const int* in_sizes, int n_in,
                              void* d_out, int out_size, void* d_ws, size_t ws_size,
                              hipStream_t stream)
{
  const float* x  = (const float*)d_in[0];
  const float* Wk = (const float*)d_in[1];
  const float* bk = (const float*)d_in[2];
  const float* Wq = (const float*)d_in[3];
  const float* bq = (const float*)d_in[4];
  const float* Wv = (const float*)d_in[5];
  const float* bv = (const float*)d_in[6];
  const float* Wr = (const float*)d_in[7];
  const float* br = (const float*)d_in[8];
  // d_in[9] = head_count (constant 8, baked into kernels)
  float* out = (float*)d_out;

  float* ctx = (float*)d_ws;                                // BB*2048 floats = 32 KB
  float* M   = (float*)d_ws + (size_t)BB * HEADS * HD * HD; // BB*16384 floats = 256 KB

  (void)hipMemsetAsync(ctx, 0, (size_t)BB * HEADS * HD * HD * sizeof(float), stream);
  k1_context<<<dim3(K1_GRIDX, BB), TPB, 0, stream>>>(x, Wk, bk, Wv, bv, ctx);
  k2_fold<<<dim3(BB, 2), TPB, 0, stream>>>(Wr, ctx, M);
  k3_out<<<dim3(NTILES, BB), TPB, 0, stream>>>(x, Wq, bq, M, br, out);
}

// Round 9
// 330.059 us; speedup vs baseline: 2.6978x; 2.6978x over previous
//
#include <hip/hip_runtime.h>

#define BB 4
#define CC 128
#define NN 65536
#define HEADS 8
#define TN 32
#define NT32 (NN / TN)      // 2048 tiles per batch
#define TPB 256
#define GRIDX 128           // persistent blocks per batch (k1 & k3): 16 tiles each
#define XPAD 136            // chan-stride for XH/XL/QB rows: 272B = 16B-aligned, 2-way banks
#define SPAD 40             // space-stride for KB/VB rows: 80B = 16B-aligned

typedef __attribute__((ext_vector_type(8))) short short8;   // 8 bf16 = 4 VGPR (MFMA A/B frag)
typedef __attribute__((ext_vector_type(4))) float f32x4;    // MFMA C/D frag

#define MFMA_B16 __builtin_amdgcn_mfma_f32_16x16x32_bf16

// bf16 bit helpers. Split: x = hi(trunc) + lo(rne of residual) -> ~2^-17 rel.
__device__ inline unsigned short bf16_trunc(float f) {
  union { float f; unsigned u; } c; c.f = f; return (unsigned short)(c.u >> 16);
}
__device__ inline float bf16_to_f(unsigned short s) {
  union { float f; unsigned u; } c; c.u = ((unsigned)s) << 16; return c.f;
}
__device__ inline unsigned short bf16_rne(float f) {
  union { float f; unsigned u; } c; c.f = f;
  unsigned r = c.u + 0x7FFF + ((c.u >> 16) & 1);
  return (unsigned short)(r >> 16);
}

// ---------------------------------------------------------------------------
// k1: per-head context via MFMA.
//  per tile (32 cols): K/V = W*(Xhi+Xlo) [2-term split, fp32 acc] -> relu/bias
//  -> bf16 KB/VB [chan][space] -> ctx[h] += K_h * V_h^T (one 16x16x32 per head).
//  Fragment layouts (m89-verified): A row=l&15,k=(l>>4)*8+e; B col=l&15,k同;
//  D col=l&15,row=(l>>4)*4+reg.
// ---------------------------------------------------------------------------
__global__ __launch_bounds__(TPB, 2) void k1_context(
    const float* __restrict__ x,
    const float* __restrict__ Wk, const float* __restrict__ bk,
    const float* __restrict__ Wv, const float* __restrict__ bv,
    float* __restrict__ ctx)
{
  __shared__ unsigned short XH[TN][XPAD];   // 8.7 KB  [col][chan]
  __shared__ unsigned short XL[TN][XPAD];   // 8.7 KB
  __shared__ unsigned short KB[CC][SPAD];   // 10.2 KB [chan][space]
  __shared__ unsigned short VB[CC][SPAD];   // 10.2 KB  -> 37.9 KB total

  const int b = blockIdx.y;
  const int t = threadIdx.x;
  const int w = t >> 6, lane = t & 63;
  const int l15 = lane & 15, lhi = lane >> 4;
  const int rowbase = w * 32;               // this wave's 32 out-chans

  // ---- hoist W fragments (pure bf16) + biases: loop-invariant over tiles ----
  short8 wk[2][4], wv[2][4];
#pragma unroll
  for (int mb = 0; mb < 2; ++mb)
#pragma unroll
    for (int kb = 0; kb < 4; ++kb) {
      const int row = rowbase + mb * 16 + l15;
      const int k0  = kb * 32 + lhi * 8;
      float wkf[8], wvf[8];
      *(float4*)&wkf[0] = *(const float4*)&Wk[row * CC + k0];
      *(float4*)&wkf[4] = *(const float4*)&Wk[row * CC + k0 + 4];
      *(float4*)&wvf[0] = *(const float4*)&Wv[row * CC + k0];
      *(float4*)&wvf[4] = *(const float4*)&Wv[row * CC + k0 + 4];
      unsigned short uk[8], uv[8];
#pragma unroll
      for (int e = 0; e < 8; ++e) { uk[e] = bf16_rne(wkf[e]); uv[e] = bf16_rne(wvf[e]); }
      wk[mb][kb] = *(short8*)uk;
      wv[mb][kb] = *(short8*)uv;
    }
  float bK[2][4], bV[2][4];
#pragma unroll
  for (int mb = 0; mb < 2; ++mb)
#pragma unroll
    for (int r = 0; r < 4; ++r) {
      bK[mb][r] = bk[rowbase + mb * 16 + lhi * 4 + r];
      bV[mb][r] = bv[rowbase + mb * 16 + lhi * 4 + r];
    }

  f32x4 cacc[2];
#pragma unroll
  for (int hh = 0; hh < 2; ++hh)
#pragma unroll
    for (int r = 0; r < 4; ++r) cacc[hh][r] = 0.f;

  const float* xb = x + (size_t)b * CC * NN;
  const int g = t & 7, r0 = t >> 3;

  for (int tile = blockIdx.x; tile < NT32; tile += GRIDX) {
    const int nbase = tile * TN;

    // ---- stage X tile: fp32 global -> (hi,lo) bf16 LDS, [col][chan] ----
#pragma unroll
    for (int kk = 0; kk < 4; ++kk) {
      const int row = r0 + 32 * kk;
      float vals[4];
      *(float4*)vals = *(const float4*)&xb[(size_t)row * NN + nbase + g * 4];
#pragma unroll
      for (int j = 0; j < 4; ++j) {
        const int col = g * 4 + j;
        const unsigned short hi = bf16_trunc(vals[j]);
        XH[col][row] = hi;
        XL[col][row] = bf16_rne(vals[j] - bf16_to_f(hi));
      }
    }
    __syncthreads();

    // ---- K/V projections: 2-term split MFMA, fp32 accumulate ----
    f32x4 aK[2][2], aV[2][2];
#pragma unroll
    for (int mb = 0; mb < 2; ++mb)
#pragma unroll
      for (int nb = 0; nb < 2; ++nb)
#pragma unroll
        for (int r = 0; r < 4; ++r) { aK[mb][nb][r] = 0.f; aV[mb][nb][r] = 0.f; }

#pragma unroll
    for (int nb = 0; nb < 2; ++nb) {
      const int col = nb * 16 + l15;
#pragma unroll
      for (int kb = 0; kb < 4; ++kb) {
        const short8 bh = *(const short8*)&XH[col][kb * 32 + lhi * 8];
        const short8 bl = *(const short8*)&XL[col][kb * 32 + lhi * 8];
#pragma unroll
        for (int mb = 0; mb < 2; ++mb) {
          aK[mb][nb] = MFMA_B16(wk[mb][kb], bh, aK[mb][nb], 0, 0, 0);
          aK[mb][nb] = MFMA_B16(wk[mb][kb], bl, aK[mb][nb], 0, 0, 0);
          aV[mb][nb] = MFMA_B16(wv[mb][kb], bh, aV[mb][nb], 0, 0, 0);
          aV[mb][nb] = MFMA_B16(wv[mb][kb], bl, aV[mb][nb], 0, 0, 0);
        }
      }
    }

    // ---- epilogue: bias (+relu for K), bf16, -> KB/VB [chan][space] ----
#pragma unroll
    for (int mb = 0; mb < 2; ++mb)
#pragma unroll
      for (int nb = 0; nb < 2; ++nb)
#pragma unroll
        for (int r = 0; r < 4; ++r) {
          const int chan = rowbase + mb * 16 + lhi * 4 + r;
          const int col  = nb * 16 + l15;
          KB[chan][col] = bf16_rne(fmaxf(aK[mb][nb][r] + bK[mb][r], 0.f));
          VB[chan][col] = bf16_rne(aV[mb][nb][r] + bV[mb][r]);
        }
    __syncthreads();

    // ---- ctx[h] += K_h V_h^T : one MFMA per head, 2 heads per wave ----
#pragma unroll
    for (int hh = 0; hh < 2; ++hh) {
      const int h = w * 2 + hh;
      const short8 af = *(const short8*)&KB[h * 16 + l15][lhi * 8];
      const short8 bf = *(const short8*)&VB[h * 16 + l15][lhi * 8];
      cacc[hh] = MFMA_B16(af, bf, cacc[hh], 0, 0, 0);
    }
  }

  // ---- final: ctx[b][h][i][j] += cacc (D: i=(l>>4)*4+r, j=l&15) ----
#pragma unroll
  for (int hh = 0; hh < 2; ++hh) {
    const int h = w * 2 + hh;
#pragma unroll
    for (int r = 0; r < 4; ++r) {
      const int i = lhi * 4 + r, j = l15;
      atomicAdd(&ctx[((size_t)(b * HEADS + h) * 16 + i) * 16 + j], cacc[hh][r]);
    }
  }
}

// ---------------------------------------------------------------------------
// k2: M[b][o][h*16+i] = sum_j Wr[o,h*16+j]*ctx[b,h,i,j]; write bf16 hi/lo planes
// ---------------------------------------------------------------------------
__global__ __launch_bounds__(TPB) void k2_fold(
    const float* __restrict__ Wr, const float* __restrict__ ctx,
    unsigned short* __restrict__ Mhi, unsigned short* __restrict__ Mlo)
{
  const int b = blockIdx.x;
  const int half = blockIdx.y;
  const float* cb = ctx + (size_t)b * HEADS * 16 * 16;
  const int base = half * (CC / 2) * CC;
  for (int k = threadIdx.x; k < (CC / 2) * CC; k += TPB) {
    const int idx = base + k;
    const int o = idx >> 7, c = idx & (CC - 1);
    const int h = c >> 4, i = c & 15;
    const float* cr = cb + h * 256 + i * 16;
    const float* wr = Wr + o * CC + h * 16;
    float s = 0.f;
#pragma unroll
    for (int j = 0; j < 16; ++j) s = fmaf(wr[j], cr[j], s);
    const unsigned short hi = bf16_trunc(s);
    Mhi[((size_t)b << 14) + idx] = hi;
    Mlo[((size_t)b << 14) + idx] = bf16_rne(s - bf16_to_f(hi));
  }
}

// ---------------------------------------------------------------------------
// k3: out = (Mhi+Mlo) @ relu(Wq (Xhi+Xlo) + bq) + br, all MFMA.
// QB stored [col][chan] (K-dim of the out-GEMM is qchan -> chan-contiguous).
// ---------------------------------------------------------------------------
__global__ __launch_bounds__(TPB, 2) void k3_out(
    const float* __restrict__ x,
    const float* __restrict__ Wq, const float* __restrict__ bq,
    const unsigned short* __restrict__ Mhi, const unsigned short* __restrict__ Mlo,
    const float* __restrict__ br,
    float* __restrict__ out)
{
  __shared__ unsigned short XH[TN][XPAD];   // [col][chan]
  __shared__ unsigned short XL[TN][XPAD];
  __shared__ unsigned short QB[TN][XPAD];   // [col][chan]  -> 26.1 KB total

  const int b = blockIdx.y;
  const int t = threadIdx.x;
  const int w = t >> 6, lane = t & 63;
  const int l15 = lane & 15, lhi = lane >> 4;
  const int rowbase = w * 32;

  // ---- hoist Wq (bf16) and M (hi/lo) fragments + biases ----
  short8 wq[2][4], mh[2][4], ml[2][4];
#pragma unroll
  for (int mb = 0; mb < 2; ++mb)
#pragma unroll
    for (int kb = 0; kb < 4; ++kb) {
      const int row = rowbase + mb * 16 + l15;
      const int k0  = kb * 32 + lhi * 8;
      float wqf[8];
      *(float4*)&wqf[0] = *(const float4*)&Wq[row * CC + k0];
      *(float4*)&wqf[4] = *(const float4*)&Wq[row * CC + k0 + 4];
      unsigned short uq[8];
#pragma unroll
      for (int e = 0; e < 8; ++e) uq[e] = bf16_rne(wqf[e]);
      wq[mb][kb] = *(short8*)uq;
      mh[mb][kb] = *(const short8*)&Mhi[((size_t)b << 14) + row * CC + k0];
      ml[mb][kb] = *(const short8*)&Mlo[((size_t)b << 14) + row * CC + k0];
    }
  float bQ[2][4], bR[2][4];
#pragma unroll
  for (int mb = 0; mb < 2; ++mb)
#pragma unroll
    for (int r = 0; r < 4; ++r) {
      bQ[mb][r] = bq[rowbase + mb * 16 + lhi * 4 + r];
      bR[mb][r] = br[rowbase + mb * 16 + lhi * 4 + r];
    }

  const float* xb = x + (size_t)b * CC * NN;
  const int g = t & 7, r0 = t >> 3;

  for (int tile = blockIdx.x; tile < NT32; tile += GRIDX) {
    const int nbase = tile * TN;

    // ---- stage X (hi/lo) ----
#pragma unroll
    for (int kk = 0; kk < 4; ++kk) {
      const int row = r0 + 32 * kk;
      float vals[4];
      *(float4*)vals = *(const float4*)&xb[(size_t)row * NN + nbase + g * 4];
#pragma unroll
      for (int j = 0; j < 4; ++j) {
        const int col = g * 4 + j;
        const unsigned short hi = bf16_trunc(vals[j]);
        XH[col][row] = hi;
        XL[col][row] = bf16_rne(vals[j] - bf16_to_f(hi));
      }
    }
    __syncthreads();

    // ---- Q projection (2-term split), relu, -> QB [col][chan] ----
    f32x4 aQ[2][2];
#pragma unroll
    for (int mb = 0; mb < 2; ++mb)
#pragma unroll
      for (int nb = 0; nb < 2; ++nb)
#pragma unroll
        for (int r = 0; r < 4; ++r) aQ[mb][nb][r] = 0.f;

#pragma unroll
    for (int nb = 0; nb < 2; ++nb) {
      const int col = nb * 16 + l15;
#pragma unroll
      for (int kb = 0; kb < 4; ++kb) {
        const short8 bh = *(const short8*)&XH[col][kb * 32 + lhi * 8];
        const short8 bl = *(const short8*)&XL[col][kb * 32 + lhi * 8];
#pragma unroll
        for (int mb = 0; mb < 2; ++mb) {
          aQ[mb][nb] = MFMA_B16(wq[mb][kb], bh, aQ[mb][nb], 0, 0, 0);
          aQ[mb][nb] = MFMA_B16(wq[mb][kb], bl, aQ[mb][nb], 0, 0, 0);
        }
      }
    }
#pragma unroll
    for (int mb = 0; mb < 2; ++mb)
#pragma unroll
      for (int nb = 0; nb < 2; ++nb)
#pragma unroll
        for (int r = 0; r < 4; ++r) {
          const int chan = rowbase + mb * 16 + lhi * 4 + r;
          QB[nb * 16 + l15][chan] = bf16_rne(fmaxf(aQ[mb][nb][r] + bQ[mb][r], 0.f));
        }
    __syncthreads();

    // ---- out = M @ Q (+br): 2-term M split ----
    f32x4 aO[2][2];
#pragma unroll
    for (int mb = 0; mb < 2; ++mb)
#pragma unroll
      for (int nb = 0; nb < 2; ++nb)
#pragma unroll
        for (int r = 0; r < 4; ++r) aO[mb][nb][r] = 0.f;

#pragma unroll
    for (int nb = 0; nb < 2; ++nb) {
      const int col = nb * 16 + l15;
#pragma unroll
      for (int kb = 0; kb < 4; ++kb) {
        const short8 qf = *(const short8*)&QB[col][kb * 32 + lhi * 8];
#pragma unroll
        for (int mb = 0; mb < 2; ++mb) {
          aO[mb][nb] = MFMA_B16(mh[mb][kb], qf, aO[mb][nb], 0, 0, 0);
          aO[mb][nb] = MFMA_B16(ml[mb][kb], qf, aO[mb][nb], 0, 0, 0);
        }
      }
    }
#pragma unroll
    for (int mb = 0; mb < 2; ++mb)
#pragma unroll
      for (int nb = 0; nb < 2; ++nb)
#pragma unroll
        for (int r = 0; r < 4; ++r) {
          const int chan = rowbase + mb * 16 + lhi * 4 + r;
          out[((size_t)(b * CC + chan)) * NN + nbase + nb * 16 + l15] =
              aO[mb][nb][r] + bR[mb][r];
        }
    __syncthreads();  // QB reads done before next tile's Q-proj overwrites
  }
}

// ---------------------------------------------------------------------------
extern "C" void kernel_launch(void* const* d_in, const int* in_sizes, int n_in,
                              void* d_out, int out_size, void* d_ws, size_t ws_size,
                              hipStream_t stream)
{
  const float* x  = (const float*)d_in[0];
  const float* Wk = (const float*)d_in[1];
  const float* bk = (const float*)d_in[2];
  const float* Wq = (const float*)d_in[3];
  const float* bq = (const float*)d_in[4];
  const float* Wv = (const float*)d_in[5];
  const float* bv = (const float*)d_in[6];
  const float* Wr = (const float*)d_in[7];
  const float* br = (const float*)d_in[8];
  float* out = (float*)d_out;

  // ws: ctx 32KB | Mhi 128KB | Mlo 128KB  (288 KB total)
  float* ctx = (float*)d_ws;
  unsigned short* Mhi = (unsigned short*)((char*)d_ws + 32 * 1024);
  unsigned short* Mlo = (unsigned short*)((char*)d_ws + 160 * 1024);

  (void)hipMemsetAsync(ctx, 0, (size_t)BB * HEADS * 16 * 16 * sizeof(float), stream);
  k1_context<<<dim3(GRIDX, BB), TPB, 0, stream>>>(x, Wk, bk, Wv, bv, ctx);
  k2_fold<<<dim3(BB, 2), TPB, 0, stream>>>(Wr, ctx, Mhi, Mlo);
  k3_out<<<dim3(GRIDX, BB), TPB, 0, stream>>>(x, Wq, bq, Mhi, Mlo, br, out);
}